// Round 5
// baseline (733.247 us; speedup 1.0000x reference)
//
#include <hip/hip_runtime.h>

// ---------------------------------------------------------------------------
// BiGRU + concept-attention + CNN classifier forward, MI355X gfx950.
// B=64 T=128 D=300 H=256 V=30000 K=16, filters 3/4/5 x100, CLS=5.
// Round 5:
//   - GRU: 12-wave (768thr) spill-proof layout (bfr 128 VGPR vs cap 170),
//     merged xg [tok][1536], loop-top xg prefetch, h carried in registers.
//   - xg GEMM: single N=1536 GEMM, A = f32 emb gathered+converted in staging.
//   - convs: one GEMM P = feat @ Wcat^T (N=1200,K=600) + fused pool epilogue.
//   - attn: ctab hard-coded f32. Output f32 (established round 3).
// ---------------------------------------------------------------------------

typedef unsigned short u16;
typedef unsigned int u32;
typedef __attribute__((ext_vector_type(4))) u16 u16x4;
typedef __attribute__((ext_vector_type(8))) u16 u16x8;
typedef __attribute__((ext_vector_type(8))) __bf16 bf16x8;
typedef __attribute__((ext_vector_type(4))) float f32x4;

__device__ __forceinline__ float bf2f(u16 u) {
    union { u32 i; float f; } x; x.i = ((u32)u) << 16; return x.f;
}
__device__ __forceinline__ u16 f2bf(float f) {
    union { float f; u32 i; } x; x.f = f;
    u32 r = x.i + 0x7FFFu + ((x.i >> 16) & 1u);  // RNE
    return (u16)(r >> 16);
}
__device__ __forceinline__ float sigm(float x) { return 1.f / (1.f + __expf(-x)); }
__device__ __forceinline__ float tanh_(float x) {
    float e = __expf(-2.f * fabsf(x));
    float t = (1.f - e) / (1.f + e);
    return x < 0.f ? -t : t;
}

// ---------------------------------------------------------------------------
// detect_k: flags[1]=1 if concept_mask is byte-packed (else int32).
// ---------------------------------------------------------------------------
__global__ __launch_bounds__(256) void detect_k(
    const u32* __restrict__ cmask_raw, int* __restrict__ flags)
{
    __shared__ int cnt1;
    if (threadIdx.x == 0) cnt1 = 0;
    __syncthreads();
    int c1 = 0;
    for (int i = threadIdx.x; i < 1024; i += 256)
        if (cmask_raw[i] > 1u) c1++;
    if (c1) atomicAdd(&cnt1, c1);
    __syncthreads();
    if (threadIdx.x == 0) flags[1] = (cnt1 > 0) ? 1 : 0;
}

// ---------------------------------------------------------------------------
// convert_f32: round f32 buffers into bf16 in ws (weights are f32, round 2-4).
// ---------------------------------------------------------------------------
struct CvtDesc { const void* src; u16* dst; int n; };
struct CvtArgs { CvtDesc d[17]; };

__global__ __launch_bounds__(256) void convert_f32(CvtArgs a)
{
    CvtDesc de = a.d[blockIdx.y];
    int i4 = (blockIdx.x * 256 + threadIdx.x) * 4;
    if (i4 >= de.n) return;
    const float* s = (const float*)de.src + i4;
    if (i4 + 4 <= de.n) {
        u16x4 o; o[0] = f2bf(s[0]); o[1] = f2bf(s[1]); o[2] = f2bf(s[2]); o[3] = f2bf(s[3]);
        *(u16x4*)(de.dst + i4) = o;
    } else {
        for (int e = 0; e < 4 && i4 + e < de.n; ++e) de.dst[i4 + e] = f2bf(s[e]);
    }
}

// ---------------------------------------------------------------------------
__global__ __launch_bounds__(256) void build_mask(
    const void* __restrict__ cmask, int* __restrict__ mask16, const int* __restrict__ flags)
{
    int v = blockIdx.x * 256 + threadIdx.x;
    if (v >= 30000) return;
    int m = 0;
    if (flags[1]) {
        const unsigned char* p = (const unsigned char*)cmask + (size_t)v * 16;
#pragma unroll
        for (int k = 0; k < 16; ++k) if (p[k]) m |= (1 << k);
    } else {
        const int* p = (const int*)cmask + (size_t)v * 16;
#pragma unroll
        for (int k = 0; k < 16; ++k) if (p[k]) m |= (1 << k);
    }
    mask16[v] = m;
}

// ---------------------------------------------------------------------------
// repack_conv: Wcat[1200][600] bf16 from the three f32 conv weights.
// Wcat row (off + i*100 + f)[d] = convW[f][i*600 + d].
// ---------------------------------------------------------------------------
__global__ __launch_bounds__(256) void repack_conv(
    const float* __restrict__ cw0, const float* __restrict__ cw1,
    const float* __restrict__ cw2, u16* __restrict__ wcat)
{
    const int r = blockIdx.x;          // 0..1199
    const int d0 = threadIdx.x * 4;
    if (d0 >= 600) return;
    const float* src;
    if (r < 300)      { int f = r % 100,       i = r / 100;        src = cw0 + (size_t)f * 1800 + i * 600; }
    else if (r < 700) { int rr = r - 300, f = rr % 100, i = rr / 100; src = cw1 + (size_t)f * 2400 + i * 600; }
    else              { int rr = r - 700, f = rr % 100, i = rr / 100; src = cw2 + (size_t)f * 3000 + i * 600; }
    float4 x = *(const float4*)(src + d0);
    u16x4 o; o[0] = f2bf(x.x); o[1] = f2bf(x.y); o[2] = f2bf(x.z); o[3] = f2bf(x.w);
    *(u16x4*)(wcat + (size_t)r * 600 + d0) = o;
}

// ---------------------------------------------------------------------------
// Generic MFMA GEMM: C[M,N] = A[M,K] * W[N,K]^T (+ bias, opt ReLU).
// ROWMODE 0: A row m at m*lda; 1: rowidx[m]*lda (gather).
// EPI: 0 = none, 1 = +bias, 2 = +bias,ReLU. OUTBF: bf16/f32 out.
// AF32: A is f32 (converted to bf16 during staging).
// ---------------------------------------------------------------------------
template<int ROWMODE, int EPI, int OUTBF, int AF32>
__global__ __launch_bounds__(256) void gemm_bt(
    const void* __restrict__ Araw, const u16* __restrict__ W,
    const u16* __restrict__ bias, const int* __restrict__ rowidx,
    float* __restrict__ Cf, u16* __restrict__ Cb,
    int M, int N, int K, int lda, int ldc)
{
    __shared__ __align__(16) u16 sA[64 * 40];
    __shared__ __align__(16) u16 sW[64 * 40];

    const int tid = threadIdx.x;
    const int m0 = blockIdx.y * 64;
    const int n0 = blockIdx.x * 64;

    const int l  = tid & 63;
    const int w  = tid >> 6;
    const int wm = (w >> 1) << 5;
    const int wn = (w & 1) << 5;
    const int fr = l & 15;
    const int fk = (l >> 4) << 3;

    const int sr = tid >> 2;
    const int cb = (tid & 3) << 3;

    size_t abase;
    {
        int m = m0 + sr;
        if constexpr (ROWMODE == 1) abase = (size_t)rowidx[m] * (size_t)lda;
        else                        abase = (size_t)m * (size_t)lda;
    }
    const int  wrow   = n0 + sr;
    const bool wvalid = wrow < N;
    const size_t wbase = (size_t)wrow * (size_t)K;

    f32x4 acc00 = {0,0,0,0}, acc01 = {0,0,0,0}, acc10 = {0,0,0,0}, acc11 = {0,0,0,0};

    for (int k0 = 0; k0 < K; k0 += 32) {
        __syncthreads();
        {   // stage A tile [64 x 32]
            u16x4 v0 = {0,0,0,0}, v1 = {0,0,0,0};
            int k = k0 + cb;
            if constexpr (AF32) {
                const float* A = (const float*)Araw;
                if (k + 8 <= K) {
                    const float* p = A + abase + k;
                    float4 x0 = *(const float4*)p;
                    float4 x1 = *(const float4*)(p + 4);
                    v0[0] = f2bf(x0.x); v0[1] = f2bf(x0.y); v0[2] = f2bf(x0.z); v0[3] = f2bf(x0.w);
                    v1[0] = f2bf(x1.x); v1[1] = f2bf(x1.y); v1[2] = f2bf(x1.z); v1[3] = f2bf(x1.w);
                } else {
#pragma unroll
                    for (int e = 0; e < 4; ++e) { int kk = k + e;     if (kk < K) v0[e] = f2bf(A[abase + kk]); }
#pragma unroll
                    for (int e = 0; e < 4; ++e) { int kk = k + 4 + e; if (kk < K) v1[e] = f2bf(A[abase + kk]); }
                }
            } else {
                const u16* A = (const u16*)Araw;
                if (k + 8 <= K) {
                    const u16* p = A + abase + k;
                    v0 = *(const u16x4*)p;
                    v1 = *(const u16x4*)(p + 4);
                } else {
#pragma unroll
                    for (int e = 0; e < 4; ++e) { int kk = k + e;     if (kk < K) v0[e] = A[abase + kk]; }
#pragma unroll
                    for (int e = 0; e < 4; ++e) { int kk = k + 4 + e; if (kk < K) v1[e] = A[abase + kk]; }
                }
            }
            *(u16x4*)(sA + sr * 40 + cb)     = v0;
            *(u16x4*)(sA + sr * 40 + cb + 4) = v1;
        }
        {   // stage W tile [64 x 32]
            u16x4 v0 = {0,0,0,0}, v1 = {0,0,0,0};
            int k = k0 + cb;
            if (wvalid) {
                if (k + 8 <= K) {
                    const u16* p = W + wbase + k;
                    v0 = *(const u16x4*)p;
                    v1 = *(const u16x4*)(p + 4);
                } else {
#pragma unroll
                    for (int e = 0; e < 4; ++e) { int kk = k + e;     if (kk < K) v0[e] = W[wbase + kk]; }
#pragma unroll
                    for (int e = 0; e < 4; ++e) { int kk = k + 4 + e; if (kk < K) v1[e] = W[wbase + kk]; }
                }
            }
            *(u16x4*)(sW + sr * 40 + cb)     = v0;
            *(u16x4*)(sW + sr * 40 + cb + 4) = v1;
        }
        __syncthreads();

        bf16x8 a0 = *(const bf16x8*)(sA + (wm + fr)      * 40 + fk);
        bf16x8 a1 = *(const bf16x8*)(sA + (wm + 16 + fr) * 40 + fk);
        bf16x8 b0 = *(const bf16x8*)(sW + (wn + fr)      * 40 + fk);
        bf16x8 b1 = *(const bf16x8*)(sW + (wn + 16 + fr) * 40 + fk);

        acc00 = __builtin_amdgcn_mfma_f32_16x16x32_bf16(a0, b0, acc00, 0, 0, 0);
        acc01 = __builtin_amdgcn_mfma_f32_16x16x32_bf16(a0, b1, acc01, 0, 0, 0);
        acc10 = __builtin_amdgcn_mfma_f32_16x16x32_bf16(a1, b0, acc10, 0, 0, 0);
        acc11 = __builtin_amdgcn_mfma_f32_16x16x32_bf16(a1, b1, acc11, 0, 0, 0);
    }

    const int rb = (l >> 4) << 2;
    const int cc = l & 15;
#define EPILOG(ACC, I, J)                                                     \
    {                                                                         \
        int col = n0 + wn + (J)*16 + cc;                                      \
        if (col < N) {                                                        \
            float bv = (EPI >= 1) ? bf2f(bias[col]) : 0.f;                    \
            _Pragma("unroll")                                                 \
            for (int r = 0; r < 4; ++r) {                                     \
                int row = m0 + wm + (I)*16 + rb + r;                          \
                if (row < M) {                                                \
                    float v = ACC[r] + bv;                                    \
                    if (EPI == 2) v = fmaxf(v, 0.f);                          \
                    if (OUTBF) Cb[(size_t)row * ldc + col] = f2bf(v);         \
                    else       Cf[(size_t)row * ldc + col] = v;               \
                }                                                             \
            }                                                                 \
        }                                                                     \
    }
    EPILOG(acc00, 0, 0); EPILOG(acc01, 0, 1); EPILOG(acc10, 1, 0); EPILOG(acc11, 1, 1);
#undef EPILOG
}

// ---------------------------------------------------------------------------
// GRU scan, MFMA + register-resident Wh. 12 waves x 64 cols (spill-proof:
// bfr = 128 VGPR vs cap 170 at 3 waves/SIMD).
// grid (8 batch-groups, 2 dirs) x 768 threads.
// Per step: loop-top xg prefetch -> 32 MFMA/wave -> gh to LDS -> barrier ->
// waves 0..7 pointwise (h in registers) -> barrier.
// ---------------------------------------------------------------------------
#define GB 8
__global__ __launch_bounds__(768, 3) void gru_scan_mfma(
    const u16* __restrict__ xg,           // [8192][1536], fwd cols 0..767
    const u16* __restrict__ whf, const u16* __restrict__ whb,
    const u16* __restrict__ bhf, const u16* __restrict__ bhb,
    u16* __restrict__ outb)
{
    const int bg  = blockIdx.x;
    const int dir = blockIdx.y;
    const u16* wh = dir ? whb : whf;
    const u16* bh = dir ? bhb : bhf;

    const int tid = threadIdx.x;
    const int w = tid >> 6;      // wave 0..11
    const int l = tid & 63;

    __shared__ __align__(16) u16 h_bf[16][264];   // rows 8..15 stay zero
    __shared__ __align__(16) float gh[GB][772];
    __shared__ float bh_s[768];

    for (int i = tid; i < 16 * 264; i += 768) ((u16*)h_bf)[i] = 0;
    bh_s[tid] = bf2f(bh[tid]);

    // B fragments: lane l holds Wh[n][k..k+7], n = w*64 + c*16 + (l&15),
    // k = kt*32 + (l>>4)*8  (layout verified by gemm_bt pass).
    bf16x8 bfr[4][8];
#pragma unroll
    for (int c = 0; c < 4; ++c)
#pragma unroll
        for (int kt = 0; kt < 8; ++kt) {
            const int n = w * 64 + c * 16 + (l & 15);
            const int k = kt * 32 + (l >> 4) * 8;
            bfr[c][kt] = *(const bf16x8*)(wh + (size_t)n * 256 + k);
        }

    const int qrow = (l >> 4) << 2;
    const int arow = l & 15;
    const int aofs = (l >> 4) << 3;
    const int j0 = l * 4;
    const int bglob = bg * GB + w;       // valid for w < GB
    f32x4 hreg = {0.f, 0.f, 0.f, 0.f};

    __syncthreads();

    for (int s = 0; s < 128; ++s) {
        const int t = dir ? (127 - s) : s;

        // loop-top xg prefetch (consumed after the MFMA phase -> latency hidden)
        u16x4 xr4 = {0,0,0,0}, xz4 = {0,0,0,0}, xn4 = {0,0,0,0};
        if (w < GB) {
            const size_t tb = (size_t)(bglob * 128 + t) * 1536 + dir * 768;
            xr4 = *(const u16x4*)(xg + tb + j0);
            xz4 = *(const u16x4*)(xg + tb + 256 + j0);
            xn4 = *(const u16x4*)(xg + tb + 512 + j0);
        }

        // --- GEMM phase: gh[0:GB][0:768] = h @ Wh^T
        f32x4 acc[4];
#pragma unroll
        for (int c = 0; c < 4; ++c) acc[c] = (f32x4){0.f, 0.f, 0.f, 0.f};
#pragma unroll
        for (int kt = 0; kt < 8; ++kt) {
            bf16x8 a = *(const bf16x8*)(&h_bf[arow][kt * 32 + aofs]);
#pragma unroll
            for (int c = 0; c < 4; ++c)
                acc[c] = __builtin_amdgcn_mfma_f32_16x16x32_bf16(a, bfr[c][kt], acc[c], 0, 0, 0);
        }
        if (qrow < GB) {
#pragma unroll
            for (int c = 0; c < 4; ++c) {
                const int col = w * 64 + c * 16 + (l & 15);
#pragma unroll
                for (int r = 0; r < 4; ++r)
                    gh[qrow + r][col] = acc[c][r];
            }
        }
        __syncthreads();

        // --- pointwise: wave w (<8) = batch row w, lane l = units j0..j0+3
        if (w < GB) {
            f32x4 gr = *(const f32x4*)(&gh[w][j0]);
            f32x4 gz = *(const f32x4*)(&gh[w][256 + j0]);
            f32x4 gn = *(const f32x4*)(&gh[w][512 + j0]);
            f32x4 br = *(const f32x4*)(&bh_s[j0]);
            f32x4 bz = *(const f32x4*)(&bh_s[256 + j0]);
            f32x4 bn = *(const f32x4*)(&bh_s[512 + j0]);
            u16x4 ho;
#pragma unroll
            for (int e = 0; e < 4; ++e) {
                float r = sigm(bf2f(xr4[e]) + gr[e] + br[e]);
                float z = sigm(bf2f(xz4[e]) + gz[e] + bz[e]);
                float n = tanh_(bf2f(xn4[e]) + r * (gn[e] + bn[e]));
                float h2 = (1.f - z) * n + z * hreg[e];
                hreg[e] = h2;
                ho[e] = f2bf(h2);
            }
            *(u16x4*)(&h_bf[w][j0]) = ho;
            *(u16x4*)(outb + (size_t)(bglob * 128 + t) * 512 + dir * 256 + j0) = ho;
        }
        __syncthreads();
    }
}
#undef GB

// ---------------------------------------------------------------------------
// Concept attention. ctab is f32. Reads ctx from feat[:,0:300] (bf16),
// writes concept to feat[:,300:600].
// ---------------------------------------------------------------------------
__global__ __launch_bounds__(256) void attn_kernel(
    const int* __restrict__ inp, const float* __restrict__ ctab,
    const int* __restrict__ mask16, u16* __restrict__ feat)
{
    const int tok = blockIdx.x;
    const int tid = threadIdx.x;
    const int v = inp[tok];

    __shared__ float ctx_s[300];
    __shared__ __align__(16) u16 conc_s[16 * 300];
    __shared__ float sc_s[16];
    __shared__ float at_s[16];

    for (int d = tid; d < 300; d += 256) ctx_s[d] = bf2f(feat[(size_t)tok * 600 + d]);
    {
        const float4* src = (const float4*)(ctab + (size_t)v * 4800);
        for (int i = tid; i < 1200; i += 256) {
            float4 x = src[i];
            u16x4 o; o[0] = f2bf(x.x); o[1] = f2bf(x.y); o[2] = f2bf(x.z); o[3] = f2bf(x.w);
            *(u16x4*)(conc_s + i * 4) = o;
        }
    }
    __syncthreads();

    const int g = tid >> 4, ln = tid & 15;
    float s = 0.f;
    for (int d = ln; d < 300; d += 16) s += bf2f(conc_s[g * 300 + d]) * ctx_s[d];
    s += __shfl_xor(s, 1); s += __shfl_xor(s, 2); s += __shfl_xor(s, 4); s += __shfl_xor(s, 8);
    if (ln == 0) sc_s[g] = ((mask16[v] >> g) & 1) ? s : -1e30f;
    __syncthreads();

    if (tid == 0) {
        float m = -1e30f;
#pragma unroll
        for (int i = 0; i < 16; ++i) m = fmaxf(m, sc_s[i]);
        float p[16]; float den = 0.f;
#pragma unroll
        for (int i = 0; i < 16; ++i) {
            float pe = (sc_s[i] <= -1e29f) ? 0.f : __expf(sc_s[i] - m);
            p[i] = pe; den += pe;
        }
        float inv = den > 0.f ? 1.f / den : 0.f;
#pragma unroll
        for (int i = 0; i < 16; ++i) at_s[i] = p[i] * inv;
    }
    __syncthreads();

    for (int d = tid; d < 300; d += 256) {
        float a = 0.f;
#pragma unroll
        for (int g2 = 0; g2 < 16; ++g2) a += at_s[g2] * bf2f(conc_s[g2 * 300 + d]);
        feat[(size_t)tok * 600 + 300 + d] = f2bf(a);
    }
}

// ---------------------------------------------------------------------------
// pool_fused: c[b,l,f] = bias + sum_i P[b,l+i, off+i*100+f]; out = relu(max_l c)
// ---------------------------------------------------------------------------
__global__ __launch_bounds__(128) void pool_fused(
    const u16* __restrict__ P, const u16* __restrict__ cbcat,
    float* __restrict__ pool)
{
    const int b = blockIdx.x, which = blockIdx.y, f = threadIdx.x;
    if (f >= 100) return;
    const int fs  = which == 0 ? 3 : (which == 1 ? 4 : 5);
    const int off = which == 0 ? 0 : (which == 1 ? 300 : 700);
    const int L   = 128 - fs + 1;
    const float bias = bf2f(cbcat[which * 100 + f]);
    float mm = -1e30f;
    for (int l2 = 0; l2 < L; ++l2) {
        float s = bias;
#pragma unroll 5
        for (int i = 0; i < fs; ++i)
            s += bf2f(P[(size_t)(b * 128 + l2 + i) * 1200 + off + i * 100 + f]);
        mm = fmaxf(mm, s);
    }
    pool[b * 300 + which * 100 + f] = fmaxf(mm, 0.f);
}

// ---------------------------------------------------------------------------
__global__ __launch_bounds__(128) void final_k(
    const float* __restrict__ pool,
    const u16* __restrict__ fc1W, const u16* __restrict__ fc1b,
    const u16* __restrict__ fc2W, const u16* __restrict__ fc2b,
    float* __restrict__ out)
{
    const int b = blockIdx.x, tid = threadIdx.x;
    __shared__ float ps[300], h1[100], lg[5];
    for (int d = tid; d < 300; d += 128) ps[d] = pool[b * 300 + d];
    __syncthreads();
    if (tid < 100) {
        float a = bf2f(fc1b[tid]);
        for (int k = 0; k < 300; ++k) a += bf2f(fc1W[tid * 300 + k]) * ps[k];
        h1[tid] = a;
    }
    __syncthreads();
    if (tid < 5) {
        float a = bf2f(fc2b[tid]);
        for (int k = 0; k < 100; ++k) a += bf2f(fc2W[tid * 100 + k]) * h1[k];
        lg[tid] = a;
    }
    __syncthreads();
    if (tid == 0) {
        float m = fmaxf(fmaxf(fmaxf(lg[0], lg[1]), fmaxf(lg[2], lg[3])), lg[4]);
        float e0 = __expf(lg[0] - m), e1 = __expf(lg[1] - m), e2 = __expf(lg[2] - m),
              e3 = __expf(lg[3] - m), e4 = __expf(lg[4] - m);
        float inv = 1.f / (e0 + e1 + e2 + e3 + e4);
        out[b * 5 + 0] = e0 * inv;
        out[b * 5 + 1] = e1 * inv;
        out[b * 5 + 2] = e2 * inv;
        out[b * 5 + 3] = e3 * inv;
        out[b * 5 + 4] = e4 * inv;
    }
}

// ---------------------------------------------------------------------------
extern "C" void kernel_launch(void* const* d_in, const int* in_sizes, int n_in,
                              void* d_out, int out_size, void* d_ws, size_t ws_size,
                              hipStream_t stream)
{
    (void)in_sizes; (void)n_in; (void)out_size; (void)ws_size;

    const int*  inp     = (const int*)d_in[0];
    const void* embR    = d_in[1];
    const void* WxfR    = d_in[2];
    const void* WhfR    = d_in[3];
    const void* bxfR    = d_in[4];
    const void* bhfR    = d_in[5];
    const void* WxbR    = d_in[6];
    const void* WhbR    = d_in[7];
    const void* bxbR    = d_in[8];
    const void* bhbR    = d_in[9];
    const void* fc1cWR  = d_in[10];
    const void* fc1cbR  = d_in[11];
    const void* ctabR   = d_in[12];
    const void* cmaskR  = d_in[13];
    const void* cw0R    = d_in[14];
    const void* cb0R    = d_in[15];
    const void* cw1R    = d_in[16];
    const void* cb1R    = d_in[17];
    const void* cw2R    = d_in[18];
    const void* cb2R    = d_in[19];
    const void* fc1WR   = d_in[20];
    const void* fc1bR   = d_in[21];
    const void* fc2WR   = d_in[22];
    const void* fc2bR   = d_in[23];

    char* ws = (char*)d_ws;
    size_t off = 0;
    auto alloc = [&](size_t bytes) -> char* {
        char* r = ws + off;
        off = (off + bytes + 255) & ~(size_t)255;
        return r;
    };

    u16*   xgc    = (u16*)alloc(8192ull * 1536 * 2);   // merged fwd/bwd gates
    u16*   outb   = (u16*)alloc(8192ull * 512 * 2);
    u16*   feat   = (u16*)alloc(8192ull * 600 * 2);
    u16*   P      = (u16*)alloc(8192ull * 1200 * 2);
    float* pool   = (float*)alloc(64ull * 300 * 4);
    int*   flags  = (int*)alloc(256);
    int*   mask16 = (int*)alloc(30000ull * 4);
    u16*   wxcat  = (u16*)alloc(1536ull * 300 * 2);
    u16*   bxcat  = (u16*)alloc(1536ull * 2);
    u16*   whfc   = (u16*)alloc(196608ull * 2);
    u16*   whbc   = (u16*)alloc(196608ull * 2);
    u16*   bhfc   = (u16*)alloc(768ull * 2);
    u16*   bhbc   = (u16*)alloc(768ull * 2);
    u16*   fc1cWc = (u16*)alloc(153600ull * 2);
    u16*   fc1cbc = (u16*)alloc(300ull * 2);
    u16*   wcat   = (u16*)alloc(1200ull * 600 * 2);
    u16*   cbcat  = (u16*)alloc(300ull * 2);
    u16*   fc1Wc  = (u16*)alloc(30000ull * 2);
    u16*   fc1bc  = (u16*)alloc(100ull * 2);
    u16*   fc2Wc  = (u16*)alloc(500ull * 2);
    u16*   fc2bc  = (u16*)alloc(8ull * 2);

    // 0) mask dtype detection (int32 vs byte-packed bools)
    detect_k<<<1, 256, 0, stream>>>((const u32*)cmaskR, flags);

    // 1) convert f32 weights to bf16 in ws (merged Wx/bx/conv-bias layouts)
    {
        CvtArgs a{};
        a.d[0]  = { WxfR,   wxcat,          230400 };
        a.d[1]  = { WxbR,   wxcat + 230400, 230400 };
        a.d[2]  = { bxfR,   bxcat,          768 };
        a.d[3]  = { bxbR,   bxcat + 768,    768 };
        a.d[4]  = { WhfR,   whfc,           196608 };
        a.d[5]  = { WhbR,   whbc,           196608 };
        a.d[6]  = { bhfR,   bhfc,           768 };
        a.d[7]  = { bhbR,   bhbc,           768 };
        a.d[8]  = { fc1cWR, fc1cWc,         153600 };
        a.d[9]  = { fc1cbR, fc1cbc,         300 };
        a.d[10] = { cb0R,   cbcat,          100 };
        a.d[11] = { cb1R,   cbcat + 100,    100 };
        a.d[12] = { cb2R,   cbcat + 200,    100 };
        a.d[13] = { fc1WR,  fc1Wc,          30000 };
        a.d[14] = { fc1bR,  fc1bc,          100 };
        a.d[15] = { fc2WR,  fc2Wc,          500 };
        a.d[16] = { fc2bR,  fc2bc,          5 };
        convert_f32<<<dim3(225, 17), 256, 0, stream>>>(a);
    }

    // 2) concept mask -> bitmask; conv weight repack
    build_mask<<<118, 256, 0, stream>>>(cmaskR, mask16, flags);
    repack_conv<<<1200, 256, 0, stream>>>(
        (const float*)cw0R, (const float*)cw1R, (const float*)cw2R, wcat);

    // 3) xg = emb[inp] @ [Wx_f;Wx_b]^T + [bx_f;bx_b]  (A = f32 emb, gathered)
    gemm_bt<1, 1, 1, 1><<<dim3(24, 128), 256, 0, stream>>>(
        embR, wxcat, bxcat, inp, nullptr, xgc, 8192, 1536, 300, 300, 1536);

    // 4) bidirectional GRU scan (MFMA, register-resident Wh) -> outb
    gru_scan_mfma<<<dim3(8, 2), 768, 0, stream>>>(
        xgc, whfc, whbc, bhfc, bhbc, outb);

    // 5) ctx = outb @ fc1c_W^T + b -> feat[:, 0:300]
    gemm_bt<0, 1, 1, 0><<<dim3(5, 128), 256, 0, stream>>>(
        outb, fc1cWc, fc1cbc, nullptr, nullptr, feat, 8192, 300, 512, 512, 600);

    // 6) concept attention -> feat[:, 300:600]
    attn_kernel<<<dim3(8192), 256, 0, stream>>>(inp, (const float*)ctabR, mask16, feat);

    // 7) P = feat @ Wcat^T  (one GEMM for all three conv filter banks)
    gemm_bt<0, 0, 1, 0><<<dim3(19, 128), 256, 0, stream>>>(
        feat, wcat, nullptr, nullptr, nullptr, P, 8192, 1200, 600, 600, 1200);

    // 8) shift-add + bias + relu + maxpool
    pool_fused<<<dim3(64, 3), 128, 0, stream>>>(P, cbcat, pool);

    // 9) fc1 -> fc2 -> softmax -> d_out (f32)
    final_k<<<dim3(64), 128, 0, stream>>>(pool, fc1Wc, fc1bc, fc2Wc, fc2bc, (float*)d_out);
}

// Round 6
// 551.155 us; speedup vs baseline: 1.3304x; 1.3304x over previous
//
#include <hip/hip_runtime.h>

// ---------------------------------------------------------------------------
// BiGRU + concept-attention + CNN classifier forward, MI355X gfx950.
// B=64 T=128 D=300 H=256 V=30000 K=16, filters 3/4/5 x100, CLS=5.
// Round 6: GRU weights pinned in VGPRs via opaque asm redefinition
// ("+v" on each fragment) -- round-5 profile proved the allocator
// rematerializes the Wh loads inside the step loop otherwise (VGPR=84).
// Geometry: 8 waves x 96 cols, GB=8, launch_bounds(512,2) -> 256 cap,
// need ~240. Everything else as round 5.
// ---------------------------------------------------------------------------

typedef unsigned short u16;
typedef unsigned int u32;
typedef __attribute__((ext_vector_type(4))) u16 u16x4;
typedef __attribute__((ext_vector_type(8))) u16 u16x8;
typedef __attribute__((ext_vector_type(8))) __bf16 bf16x8;
typedef __attribute__((ext_vector_type(4))) float f32x4;

__device__ __forceinline__ float bf2f(u16 u) {
    union { u32 i; float f; } x; x.i = ((u32)u) << 16; return x.f;
}
__device__ __forceinline__ u16 f2bf(float f) {
    union { float f; u32 i; } x; x.f = f;
    u32 r = x.i + 0x7FFFu + ((x.i >> 16) & 1u);  // RNE
    return (u16)(r >> 16);
}
__device__ __forceinline__ float sigm(float x) { return 1.f / (1.f + __expf(-x)); }
__device__ __forceinline__ float tanh_(float x) {
    float e = __expf(-2.f * fabsf(x));
    float t = (1.f - e) / (1.f + e);
    return x < 0.f ? -t : t;
}

// ---------------------------------------------------------------------------
__global__ __launch_bounds__(256) void detect_k(
    const u32* __restrict__ cmask_raw, int* __restrict__ flags)
{
    __shared__ int cnt1;
    if (threadIdx.x == 0) cnt1 = 0;
    __syncthreads();
    int c1 = 0;
    for (int i = threadIdx.x; i < 1024; i += 256)
        if (cmask_raw[i] > 1u) c1++;
    if (c1) atomicAdd(&cnt1, c1);
    __syncthreads();
    if (threadIdx.x == 0) flags[1] = (cnt1 > 0) ? 1 : 0;
}

// ---------------------------------------------------------------------------
struct CvtDesc { const void* src; u16* dst; int n; };
struct CvtArgs { CvtDesc d[17]; };

__global__ __launch_bounds__(256) void convert_f32(CvtArgs a)
{
    CvtDesc de = a.d[blockIdx.y];
    int i4 = (blockIdx.x * 256 + threadIdx.x) * 4;
    if (i4 >= de.n) return;
    const float* s = (const float*)de.src + i4;
    if (i4 + 4 <= de.n) {
        u16x4 o; o[0] = f2bf(s[0]); o[1] = f2bf(s[1]); o[2] = f2bf(s[2]); o[3] = f2bf(s[3]);
        *(u16x4*)(de.dst + i4) = o;
    } else {
        for (int e = 0; e < 4 && i4 + e < de.n; ++e) de.dst[i4 + e] = f2bf(s[e]);
    }
}

// ---------------------------------------------------------------------------
__global__ __launch_bounds__(256) void build_mask(
    const void* __restrict__ cmask, int* __restrict__ mask16, const int* __restrict__ flags)
{
    int v = blockIdx.x * 256 + threadIdx.x;
    if (v >= 30000) return;
    int m = 0;
    if (flags[1]) {
        const unsigned char* p = (const unsigned char*)cmask + (size_t)v * 16;
#pragma unroll
        for (int k = 0; k < 16; ++k) if (p[k]) m |= (1 << k);
    } else {
        const int* p = (const int*)cmask + (size_t)v * 16;
#pragma unroll
        for (int k = 0; k < 16; ++k) if (p[k]) m |= (1 << k);
    }
    mask16[v] = m;
}

// ---------------------------------------------------------------------------
__global__ __launch_bounds__(256) void repack_conv(
    const float* __restrict__ cw0, const float* __restrict__ cw1,
    const float* __restrict__ cw2, u16* __restrict__ wcat)
{
    const int r = blockIdx.x;          // 0..1199
    const int d0 = threadIdx.x * 4;
    if (d0 >= 600) return;
    const float* src;
    if (r < 300)      { int f = r % 100,       i = r / 100;        src = cw0 + (size_t)f * 1800 + i * 600; }
    else if (r < 700) { int rr = r - 300, f = rr % 100, i = rr / 100; src = cw1 + (size_t)f * 2400 + i * 600; }
    else              { int rr = r - 700, f = rr % 100, i = rr / 100; src = cw2 + (size_t)f * 3000 + i * 600; }
    float4 x = *(const float4*)(src + d0);
    u16x4 o; o[0] = f2bf(x.x); o[1] = f2bf(x.y); o[2] = f2bf(x.z); o[3] = f2bf(x.w);
    *(u16x4*)(wcat + (size_t)r * 600 + d0) = o;
}

// ---------------------------------------------------------------------------
// Generic MFMA GEMM: C[M,N] = A[M,K] * W[N,K]^T (+ bias, opt ReLU).
// ---------------------------------------------------------------------------
template<int ROWMODE, int EPI, int OUTBF, int AF32>
__global__ __launch_bounds__(256) void gemm_bt(
    const void* __restrict__ Araw, const u16* __restrict__ W,
    const u16* __restrict__ bias, const int* __restrict__ rowidx,
    float* __restrict__ Cf, u16* __restrict__ Cb,
    int M, int N, int K, int lda, int ldc)
{
    __shared__ __align__(16) u16 sA[64 * 40];
    __shared__ __align__(16) u16 sW[64 * 40];

    const int tid = threadIdx.x;
    const int m0 = blockIdx.y * 64;
    const int n0 = blockIdx.x * 64;

    const int l  = tid & 63;
    const int w  = tid >> 6;
    const int wm = (w >> 1) << 5;
    const int wn = (w & 1) << 5;
    const int fr = l & 15;
    const int fk = (l >> 4) << 3;

    const int sr = tid >> 2;
    const int cb = (tid & 3) << 3;

    size_t abase;
    {
        int m = m0 + sr;
        if constexpr (ROWMODE == 1) abase = (size_t)rowidx[m] * (size_t)lda;
        else                        abase = (size_t)m * (size_t)lda;
    }
    const int  wrow   = n0 + sr;
    const bool wvalid = wrow < N;
    const size_t wbase = (size_t)wrow * (size_t)K;

    f32x4 acc00 = {0,0,0,0}, acc01 = {0,0,0,0}, acc10 = {0,0,0,0}, acc11 = {0,0,0,0};

    for (int k0 = 0; k0 < K; k0 += 32) {
        __syncthreads();
        {   // stage A tile [64 x 32]
            u16x4 v0 = {0,0,0,0}, v1 = {0,0,0,0};
            int k = k0 + cb;
            if constexpr (AF32) {
                const float* A = (const float*)Araw;
                if (k + 8 <= K) {
                    const float* p = A + abase + k;
                    float4 x0 = *(const float4*)p;
                    float4 x1 = *(const float4*)(p + 4);
                    v0[0] = f2bf(x0.x); v0[1] = f2bf(x0.y); v0[2] = f2bf(x0.z); v0[3] = f2bf(x0.w);
                    v1[0] = f2bf(x1.x); v1[1] = f2bf(x1.y); v1[2] = f2bf(x1.z); v1[3] = f2bf(x1.w);
                } else {
#pragma unroll
                    for (int e = 0; e < 4; ++e) { int kk = k + e;     if (kk < K) v0[e] = f2bf(A[abase + kk]); }
#pragma unroll
                    for (int e = 0; e < 4; ++e) { int kk = k + 4 + e; if (kk < K) v1[e] = f2bf(A[abase + kk]); }
                }
            } else {
                const u16* A = (const u16*)Araw;
                if (k + 8 <= K) {
                    const u16* p = A + abase + k;
                    v0 = *(const u16x4*)p;
                    v1 = *(const u16x4*)(p + 4);
                } else {
#pragma unroll
                    for (int e = 0; e < 4; ++e) { int kk = k + e;     if (kk < K) v0[e] = A[abase + kk]; }
#pragma unroll
                    for (int e = 0; e < 4; ++e) { int kk = k + 4 + e; if (kk < K) v1[e] = A[abase + kk]; }
                }
            }
            *(u16x4*)(sA + sr * 40 + cb)     = v0;
            *(u16x4*)(sA + sr * 40 + cb + 4) = v1;
        }
        {   // stage W tile [64 x 32]
            u16x4 v0 = {0,0,0,0}, v1 = {0,0,0,0};
            int k = k0 + cb;
            if (wvalid) {
                if (k + 8 <= K) {
                    const u16* p = W + wbase + k;
                    v0 = *(const u16x4*)p;
                    v1 = *(const u16x4*)(p + 4);
                } else {
#pragma unroll
                    for (int e = 0; e < 4; ++e) { int kk = k + e;     if (kk < K) v0[e] = W[wbase + kk]; }
#pragma unroll
                    for (int e = 0; e < 4; ++e) { int kk = k + 4 + e; if (kk < K) v1[e] = W[wbase + kk]; }
                }
            }
            *(u16x4*)(sW + sr * 40 + cb)     = v0;
            *(u16x4*)(sW + sr * 40 + cb + 4) = v1;
        }
        __syncthreads();

        bf16x8 a0 = *(const bf16x8*)(sA + (wm + fr)      * 40 + fk);
        bf16x8 a1 = *(const bf16x8*)(sA + (wm + 16 + fr) * 40 + fk);
        bf16x8 b0 = *(const bf16x8*)(sW + (wn + fr)      * 40 + fk);
        bf16x8 b1 = *(const bf16x8*)(sW + (wn + 16 + fr) * 40 + fk);

        acc00 = __builtin_amdgcn_mfma_f32_16x16x32_bf16(a0, b0, acc00, 0, 0, 0);
        acc01 = __builtin_amdgcn_mfma_f32_16x16x32_bf16(a0, b1, acc01, 0, 0, 0);
        acc10 = __builtin_amdgcn_mfma_f32_16x16x32_bf16(a1, b0, acc10, 0, 0, 0);
        acc11 = __builtin_amdgcn_mfma_f32_16x16x32_bf16(a1, b1, acc11, 0, 0, 0);
    }

    const int rb = (l >> 4) << 2;
    const int cc = l & 15;
#define EPILOG(ACC, I, J)                                                     \
    {                                                                         \
        int col = n0 + wn + (J)*16 + cc;                                      \
        if (col < N) {                                                        \
            float bv = (EPI >= 1) ? bf2f(bias[col]) : 0.f;                    \
            _Pragma("unroll")                                                 \
            for (int r = 0; r < 4; ++r) {                                     \
                int row = m0 + wm + (I)*16 + rb + r;                          \
                if (row < M) {                                                \
                    float v = ACC[r] + bv;                                    \
                    if (EPI == 2) v = fmaxf(v, 0.f);                          \
                    if (OUTBF) Cb[(size_t)row * ldc + col] = f2bf(v);         \
                    else       Cf[(size_t)row * ldc + col] = v;               \
                }                                                             \
            }                                                                 \
        }                                                                     \
    }
    EPILOG(acc00, 0, 0); EPILOG(acc01, 0, 1); EPILOG(acc10, 1, 0); EPILOG(acc11, 1, 1);
#undef EPILOG
}

// ---------------------------------------------------------------------------
// GRU scan, MFMA + register-PINNED Wh.
// grid (8 batch-groups, 2 dirs) x 512 threads (8 waves x 96 cols).
// bfr = 192 VGPR pinned via opaque asm redefinition (prevents the allocator
// from rematerializing the Wh loads inside the step loop -- round-5 lesson:
// VGPR_Count=84 proved remat, 97% stall).
// ---------------------------------------------------------------------------
#define GB 8
__global__ __launch_bounds__(512, 2) void gru_scan_mfma(
    const u16* __restrict__ xg,           // [8192][1536], fwd cols 0..767
    const u16* __restrict__ whf, const u16* __restrict__ whb,
    const u16* __restrict__ bhf, const u16* __restrict__ bhb,
    u16* __restrict__ outb)
{
    const int bg  = blockIdx.x;
    const int dir = blockIdx.y;
    const u16* wh = dir ? whb : whf;
    const u16* bh = dir ? bhb : bhf;

    const int tid = threadIdx.x;
    const int w = tid >> 6;      // wave 0..7
    const int l = tid & 63;

    __shared__ __align__(16) u16 h_bf[16][264];   // rows 8..15 stay zero
    __shared__ __align__(16) float gh[GB][772];
    __shared__ float bh_s[768];

    for (int i = tid; i < 16 * 264; i += 512) ((u16*)h_bf)[i] = 0;
    for (int i = tid; i < 768; i += 512) bh_s[i] = bf2f(bh[i]);

    // B fragments: lane l holds Wh[n][k..k+7], n = w*96 + c*16 + (l&15),
    // k = kt*32 + (l>>4)*8  (layout verified by the passing gemm_bt).
    bf16x8 bfr[6][8];
#pragma unroll
    for (int c = 0; c < 6; ++c)
#pragma unroll
        for (int kt = 0; kt < 8; ++kt) {
            const int n = w * 96 + c * 16 + (l & 15);
            const int k = kt * 32 + (l >> 4) * 8;
            bfr[c][kt] = *(const bf16x8*)(wh + (size_t)n * 256 + k);
        }
    // PIN: opaque redefinition -- compiler can no longer re-load these from
    // global inside the loop; they must stay register-resident.
#pragma unroll
    for (int c = 0; c < 6; ++c)
#pragma unroll
        for (int kt = 0; kt < 8; ++kt)
            asm volatile("" : "+v"(bfr[c][kt]));

    const int qrow = (l >> 4) << 2;
    const int arow = l & 15;
    const int aofs = (l >> 4) << 3;
    const int j0 = l * 4;
    const int bglob = bg * GB + w;
    f32x4 hreg = {0.f, 0.f, 0.f, 0.f};

    __syncthreads();

    for (int s = 0; s < 128; ++s) {
        const int t = dir ? (127 - s) : s;

        // loop-top xg prefetch (consumed after the MFMA phase)
        const size_t tb = (size_t)(bglob * 128 + t) * 1536 + dir * 768;
        u16x4 xr4 = *(const u16x4*)(xg + tb + j0);
        u16x4 xz4 = *(const u16x4*)(xg + tb + 256 + j0);
        u16x4 xn4 = *(const u16x4*)(xg + tb + 512 + j0);

        // --- GEMM phase: gh[0:GB][0:768] = h @ Wh^T
        f32x4 acc[6];
#pragma unroll
        for (int c = 0; c < 6; ++c) acc[c] = (f32x4){0.f, 0.f, 0.f, 0.f};
#pragma unroll
        for (int kt = 0; kt < 8; ++kt) {
            bf16x8 a = *(const bf16x8*)(&h_bf[arow][kt * 32 + aofs]);
#pragma unroll
            for (int c = 0; c < 6; ++c)
                acc[c] = __builtin_amdgcn_mfma_f32_16x16x32_bf16(a, bfr[c][kt], acc[c], 0, 0, 0);
        }
        if (qrow < GB) {
#pragma unroll
            for (int c = 0; c < 6; ++c) {
                const int col = w * 96 + c * 16 + (l & 15);
#pragma unroll
                for (int r = 0; r < 4; ++r)
                    gh[qrow + r][col] = acc[c][r];
            }
        }
        __syncthreads();

        // --- pointwise: wave w = batch row w, lane l = units j0..j0+3
        {
            f32x4 gr = *(const f32x4*)(&gh[w][j0]);
            f32x4 gz = *(const f32x4*)(&gh[w][256 + j0]);
            f32x4 gn = *(const f32x4*)(&gh[w][512 + j0]);
            f32x4 br = *(const f32x4*)(&bh_s[j0]);
            f32x4 bz = *(const f32x4*)(&bh_s[256 + j0]);
            f32x4 bn = *(const f32x4*)(&bh_s[512 + j0]);
            u16x4 ho;
#pragma unroll
            for (int e = 0; e < 4; ++e) {
                float r = sigm(bf2f(xr4[e]) + gr[e] + br[e]);
                float z = sigm(bf2f(xz4[e]) + gz[e] + bz[e]);
                float n = tanh_(bf2f(xn4[e]) + r * (gn[e] + bn[e]));
                float h2 = (1.f - z) * n + z * hreg[e];
                hreg[e] = h2;
                ho[e] = f2bf(h2);
            }
            *(u16x4*)(&h_bf[w][j0]) = ho;
            *(u16x4*)(outb + (size_t)(bglob * 128 + t) * 512 + dir * 256 + j0) = ho;
        }
        __syncthreads();
    }
}
#undef GB

// ---------------------------------------------------------------------------
// Concept attention. ctab f32; ctx from feat[:,0:300]; out feat[:,300:600].
// ---------------------------------------------------------------------------
__global__ __launch_bounds__(256) void attn_kernel(
    const int* __restrict__ inp, const float* __restrict__ ctab,
    const int* __restrict__ mask16, u16* __restrict__ feat)
{
    const int tok = blockIdx.x;
    const int tid = threadIdx.x;
    const int v = inp[tok];

    __shared__ float ctx_s[300];
    __shared__ __align__(16) u16 conc_s[16 * 300];
    __shared__ float sc_s[16];
    __shared__ float at_s[16];

    for (int d = tid; d < 300; d += 256) ctx_s[d] = bf2f(feat[(size_t)tok * 600 + d]);
    {
        const float4* src = (const float4*)(ctab + (size_t)v * 4800);
        for (int i = tid; i < 1200; i += 256) {
            float4 x = src[i];
            u16x4 o; o[0] = f2bf(x.x); o[1] = f2bf(x.y); o[2] = f2bf(x.z); o[3] = f2bf(x.w);
            *(u16x4*)(conc_s + i * 4) = o;
        }
    }
    __syncthreads();

    const int g = tid >> 4, ln = tid & 15;
    float s = 0.f;
    for (int d = ln; d < 300; d += 16) s += bf2f(conc_s[g * 300 + d]) * ctx_s[d];
    s += __shfl_xor(s, 1); s += __shfl_xor(s, 2); s += __shfl_xor(s, 4); s += __shfl_xor(s, 8);
    if (ln == 0) sc_s[g] = ((mask16[v] >> g) & 1) ? s : -1e30f;
    __syncthreads();

    if (tid == 0) {
        float m = -1e30f;
#pragma unroll
        for (int i = 0; i < 16; ++i) m = fmaxf(m, sc_s[i]);
        float p[16]; float den = 0.f;
#pragma unroll
        for (int i = 0; i < 16; ++i) {
            float pe = (sc_s[i] <= -1e29f) ? 0.f : __expf(sc_s[i] - m);
            p[i] = pe; den += pe;
        }
        float inv = den > 0.f ? 1.f / den : 0.f;
#pragma unroll
        for (int i = 0; i < 16; ++i) at_s[i] = p[i] * inv;
    }
    __syncthreads();

    for (int d = tid; d < 300; d += 256) {
        float a = 0.f;
#pragma unroll
        for (int g2 = 0; g2 < 16; ++g2) a += at_s[g2] * bf2f(conc_s[g2 * 300 + d]);
        feat[(size_t)tok * 600 + 300 + d] = f2bf(a);
    }
}

// ---------------------------------------------------------------------------
__global__ __launch_bounds__(128) void pool_fused(
    const u16* __restrict__ P, const u16* __restrict__ cbcat,
    float* __restrict__ pool)
{
    const int b = blockIdx.x, which = blockIdx.y, f = threadIdx.x;
    if (f >= 100) return;
    const int fs  = which == 0 ? 3 : (which == 1 ? 4 : 5);
    const int off = which == 0 ? 0 : (which == 1 ? 300 : 700);
    const int L   = 128 - fs + 1;
    const float bias = bf2f(cbcat[which * 100 + f]);
    float mm = -1e30f;
    for (int l2 = 0; l2 < L; ++l2) {
        float s = bias;
#pragma unroll 5
        for (int i = 0; i < fs; ++i)
            s += bf2f(P[(size_t)(b * 128 + l2 + i) * 1200 + off + i * 100 + f]);
        mm = fmaxf(mm, s);
    }
    pool[b * 300 + which * 100 + f] = fmaxf(mm, 0.f);
}

// ---------------------------------------------------------------------------
__global__ __launch_bounds__(128) void final_k(
    const float* __restrict__ pool,
    const u16* __restrict__ fc1W, const u16* __restrict__ fc1b,
    const u16* __restrict__ fc2W, const u16* __restrict__ fc2b,
    float* __restrict__ out)
{
    const int b = blockIdx.x, tid = threadIdx.x;
    __shared__ float ps[300], h1[100], lg[5];
    for (int d = tid; d < 300; d += 128) ps[d] = pool[b * 300 + d];
    __syncthreads();
    if (tid < 100) {
        float a = bf2f(fc1b[tid]);
        for (int k = 0; k < 300; ++k) a += bf2f(fc1W[tid * 300 + k]) * ps[k];
        h1[tid] = a;
    }
    __syncthreads();
    if (tid < 5) {
        float a = bf2f(fc2b[tid]);
        for (int k = 0; k < 100; ++k) a += bf2f(fc2W[tid * 100 + k]) * h1[k];
        lg[tid] = a;
    }
    __syncthreads();
    if (tid == 0) {
        float m = fmaxf(fmaxf(fmaxf(lg[0], lg[1]), fmaxf(lg[2], lg[3])), lg[4]);
        float e0 = __expf(lg[0] - m), e1 = __expf(lg[1] - m), e2 = __expf(lg[2] - m),
              e3 = __expf(lg[3] - m), e4 = __expf(lg[4] - m);
        float inv = 1.f / (e0 + e1 + e2 + e3 + e4);
        out[b * 5 + 0] = e0 * inv;
        out[b * 5 + 1] = e1 * inv;
        out[b * 5 + 2] = e2 * inv;
        out[b * 5 + 3] = e3 * inv;
        out[b * 5 + 4] = e4 * inv;
    }
}

// ---------------------------------------------------------------------------
extern "C" void kernel_launch(void* const* d_in, const int* in_sizes, int n_in,
                              void* d_out, int out_size, void* d_ws, size_t ws_size,
                              hipStream_t stream)
{
    (void)in_sizes; (void)n_in; (void)out_size; (void)ws_size;

    const int*  inp     = (const int*)d_in[0];
    const void* embR    = d_in[1];
    const void* WxfR    = d_in[2];
    const void* WhfR    = d_in[3];
    const void* bxfR    = d_in[4];
    const void* bhfR    = d_in[5];
    const void* WxbR    = d_in[6];
    const void* WhbR    = d_in[7];
    const void* bxbR    = d_in[8];
    const void* bhbR    = d_in[9];
    const void* fc1cWR  = d_in[10];
    const void* fc1cbR  = d_in[11];
    const void* ctabR   = d_in[12];
    const void* cmaskR  = d_in[13];
    const void* cw0R    = d_in[14];
    const void* cb0R    = d_in[15];
    const void* cw1R    = d_in[16];
    const void* cb1R    = d_in[17];
    const void* cw2R    = d_in[18];
    const void* cb2R    = d_in[19];
    const void* fc1WR   = d_in[20];
    const void* fc1bR   = d_in[21];
    const void* fc2WR   = d_in[22];
    const void* fc2bR   = d_in[23];

    char* ws = (char*)d_ws;
    size_t off = 0;
    auto alloc = [&](size_t bytes) -> char* {
        char* r = ws + off;
        off = (off + bytes + 255) & ~(size_t)255;
        return r;
    };

    u16*   xgc    = (u16*)alloc(8192ull * 1536 * 2);
    u16*   outb   = (u16*)alloc(8192ull * 512 * 2);
    u16*   feat   = (u16*)alloc(8192ull * 600 * 2);
    u16*   P      = (u16*)alloc(8192ull * 1200 * 2);
    float* pool   = (float*)alloc(64ull * 300 * 4);
    int*   flags  = (int*)alloc(256);
    int*   mask16 = (int*)alloc(30000ull * 4);
    u16*   wxcat  = (u16*)alloc(1536ull * 300 * 2);
    u16*   bxcat  = (u16*)alloc(1536ull * 2);
    u16*   whfc   = (u16*)alloc(196608ull * 2);
    u16*   whbc   = (u16*)alloc(196608ull * 2);
    u16*   bhfc   = (u16*)alloc(768ull * 2);
    u16*   bhbc   = (u16*)alloc(768ull * 2);
    u16*   fc1cWc = (u16*)alloc(153600ull * 2);
    u16*   fc1cbc = (u16*)alloc(300ull * 2);
    u16*   wcat   = (u16*)alloc(1200ull * 600 * 2);
    u16*   cbcat  = (u16*)alloc(300ull * 2);
    u16*   fc1Wc  = (u16*)alloc(30000ull * 2);
    u16*   fc1bc  = (u16*)alloc(100ull * 2);
    u16*   fc2Wc  = (u16*)alloc(500ull * 2);
    u16*   fc2bc  = (u16*)alloc(8ull * 2);

    // 0) mask dtype detection
    detect_k<<<1, 256, 0, stream>>>((const u32*)cmaskR, flags);

    // 1) convert f32 weights to bf16 in ws
    {
        CvtArgs a{};
        a.d[0]  = { WxfR,   wxcat,          230400 };
        a.d[1]  = { WxbR,   wxcat + 230400, 230400 };
        a.d[2]  = { bxfR,   bxcat,          768 };
        a.d[3]  = { bxbR,   bxcat + 768,    768 };
        a.d[4]  = { WhfR,   whfc,           196608 };
        a.d[5]  = { WhbR,   whbc,           196608 };
        a.d[6]  = { bhfR,   bhfc,           768 };
        a.d[7]  = { bhbR,   bhbc,           768 };
        a.d[8]  = { fc1cWR, fc1cWc,         153600 };
        a.d[9]  = { fc1cbR, fc1cbc,         300 };
        a.d[10] = { cb0R,   cbcat,          100 };
        a.d[11] = { cb1R,   cbcat + 100,    100 };
        a.d[12] = { cb2R,   cbcat + 200,    100 };
        a.d[13] = { fc1WR,  fc1Wc,          30000 };
        a.d[14] = { fc1bR,  fc1bc,          100 };
        a.d[15] = { fc2WR,  fc2Wc,          500 };
        a.d[16] = { fc2bR,  fc2bc,          5 };
        convert_f32<<<dim3(225, 17), 256, 0, stream>>>(a);
    }

    // 2) concept mask -> bitmask; conv weight repack
    build_mask<<<118, 256, 0, stream>>>(cmaskR, mask16, flags);
    repack_conv<<<1200, 256, 0, stream>>>(
        (const float*)cw0R, (const float*)cw1R, (const float*)cw2R, wcat);

    // 3) xg = emb[inp] @ [Wx_f;Wx_b]^T + [bx_f;bx_b]
    gemm_bt<1, 1, 1, 1><<<dim3(24, 128), 256, 0, stream>>>(
        embR, wxcat, bxcat, inp, nullptr, xgc, 8192, 1536, 300, 300, 1536);

    // 4) bidirectional GRU scan (MFMA, register-PINNED Wh) -> outb
    gru_scan_mfma<<<dim3(8, 2), 512, 0, stream>>>(
        xgc, whfc, whbc, bhfc, bhbc, outb);

    // 5) ctx = outb @ fc1c_W^T + b -> feat[:, 0:300]
    gemm_bt<0, 1, 1, 0><<<dim3(5, 128), 256, 0, stream>>>(
        outb, fc1cWc, fc1cbc, nullptr, nullptr, feat, 8192, 300, 512, 512, 600);

    // 6) concept attention -> feat[:, 300:600]
    attn_kernel<<<dim3(8192), 256, 0, stream>>>(inp, (const float*)ctabR, mask16, feat);

    // 7) P = feat @ Wcat^T
    gemm_bt<0, 0, 1, 0><<<dim3(19, 128), 256, 0, stream>>>(
        feat, wcat, nullptr, nullptr, nullptr, P, 8192, 1200, 600, 600, 1200);

    // 8) shift-add + bias + relu + maxpool
    pool_fused<<<dim3(64, 3), 128, 0, stream>>>(P, cbcat, pool);

    // 9) fc1 -> fc2 -> softmax -> d_out (f32)
    final_k<<<dim3(64), 128, 0, stream>>>(pool, fc1Wc, fc1bc, fc2Wc, fc2bc, (float*)d_out);
}

// Round 9
// 510.124 us; speedup vs baseline: 1.4374x; 1.0804x over previous
//
#include <hip/hip_runtime.h>

// ---------------------------------------------------------------------------
// BiGRU + concept-attention + CNN classifier forward, MI355X gfx950.
// Round 9 = round 7 + THE FIX: build_bias used `c & 767` to compute c mod 768
// (768 is not a power of two -> backward-direction biases scrambled; caused
// rounds 7/8 identical absmax 1.37e-2). Also: attn zeroes feat pad cols
// 600..639 so the P GEMM never multiplies junk.
// Structure: gemm128 (global_load_lds, 128^2 tile) for xg + P; GRU v3 with
// register-pinned Wh + bias fold; feat stride 640.
// ---------------------------------------------------------------------------

typedef unsigned short u16;
typedef unsigned int u32;
typedef __attribute__((ext_vector_type(4))) u16 u16x4;
typedef __attribute__((ext_vector_type(8))) u16 u16x8;
typedef __attribute__((ext_vector_type(8))) __bf16 bf16x8;
typedef __attribute__((ext_vector_type(4))) float f32x4;

__device__ __forceinline__ float bf2f(u16 u) {
    union { u32 i; float f; } x; x.i = ((u32)u) << 16; return x.f;
}
__device__ __forceinline__ u16 f2bf(float f) {
    union { float f; u32 i; } x; x.f = f;
    u32 r = x.i + 0x7FFFu + ((x.i >> 16) & 1u);  // RNE
    return (u16)(r >> 16);
}
__device__ __forceinline__ float sigm(float x) { return 1.f / (1.f + __expf(-x)); }
__device__ __forceinline__ float tanh_(float x) {
    float e = __expf(-2.f * fabsf(x));
    float t = (1.f - e) / (1.f + e);
    return x < 0.f ? -t : t;
}
__device__ __forceinline__ void gload16(const u16* g, u16* l) {
    __builtin_amdgcn_global_load_lds(
        (const __attribute__((address_space(1))) void*)g,
        (__attribute__((address_space(3))) void*)l, 16, 0, 0);
}

// ---------------------------------------------------------------------------
__global__ __launch_bounds__(256) void detect_k(
    const u32* __restrict__ cmask_raw, int* __restrict__ flags)
{
    __shared__ int cnt1;
    if (threadIdx.x == 0) cnt1 = 0;
    __syncthreads();
    int c1 = 0;
    for (int i = threadIdx.x; i < 1024; i += 256)
        if (cmask_raw[i] > 1u) c1++;
    if (c1) atomicAdd(&cnt1, c1);
    __syncthreads();
    if (threadIdx.x == 0) flags[1] = (cnt1 > 0) ? 1 : 0;
}

// ---------------------------------------------------------------------------
struct CvtDesc { const void* src; u16* dst; int n; };
struct CvtArgs { CvtDesc d[11]; };

__global__ __launch_bounds__(256) void convert_f32(CvtArgs a)
{
    CvtDesc de = a.d[blockIdx.y];
    int i4 = (blockIdx.x * 256 + threadIdx.x) * 4;
    if (i4 >= de.n) return;
    const float* s = (const float*)de.src + i4;
    if (i4 + 4 <= de.n) {
        u16x4 o; o[0] = f2bf(s[0]); o[1] = f2bf(s[1]); o[2] = f2bf(s[2]); o[3] = f2bf(s[3]);
        *(u16x4*)(de.dst + i4) = o;
    } else {
        for (int e = 0; e < 4 && i4 + e < de.n; ++e) de.dst[i4 + e] = f2bf(s[e]);
    }
}

// ---------------------------------------------------------------------------
__global__ __launch_bounds__(256) void build_mask(
    const void* __restrict__ cmask, int* __restrict__ mask16, const int* __restrict__ flags)
{
    int v = blockIdx.x * 256 + threadIdx.x;
    if (v >= 30000) return;
    int m = 0;
    if (flags[1]) {
        const unsigned char* p = (const unsigned char*)cmask + (size_t)v * 16;
#pragma unroll
        for (int k = 0; k < 16; ++k) if (p[k]) m |= (1 << k);
    } else {
        const int* p = (const int*)cmask + (size_t)v * 16;
#pragma unroll
        for (int k = 0; k < 16; ++k) if (p[k]) m |= (1 << k);
    }
    mask16[v] = m;
}

// ---------------------------------------------------------------------------
// repack_conv: Wcat[1280][640] bf16 (rows>=1200 and cols>=600 ZERO).
// ---------------------------------------------------------------------------
__global__ __launch_bounds__(256) void repack_conv(
    const float* __restrict__ cw0, const float* __restrict__ cw1,
    const float* __restrict__ cw2, u16* __restrict__ wcat)
{
    const int r = blockIdx.x;          // 0..1279
    const int d0 = threadIdx.x * 4;
    if (d0 >= 640) return;
    u16x4 o = {0, 0, 0, 0};
    if (r < 1200 && d0 < 600) {
        const float* src;
        if (r < 300)      { int f = r % 100,       i = r / 100;          src = cw0 + (size_t)f * 1800 + i * 600; }
        else if (r < 700) { int rr = r - 300, f = rr % 100, i = rr / 100; src = cw1 + (size_t)f * 2400 + i * 600; }
        else              { int rr = r - 700, f = rr % 100, i = rr / 100; src = cw2 + (size_t)f * 3000 + i * 600; }
        float4 x = *(const float4*)(src + d0);
        o[0] = f2bf(x.x); o[1] = f2bf(x.y); o[2] = f2bf(x.z); o[3] = f2bf(x.w);
    }
    *(u16x4*)(wcat + (size_t)r * 640 + d0) = o;
}

// ---------------------------------------------------------------------------
// pack_wx: wxpad[1536][320] bf16 (cols>=300 ZERO).
// ---------------------------------------------------------------------------
__global__ __launch_bounds__(64) void pack_wx(
    const float* __restrict__ wxf, const float* __restrict__ wxb,
    u16* __restrict__ wxpad)
{
    const int n = blockIdx.x;          // 0..1535
    const float* src = n < 768 ? wxf + (size_t)n * 300 : wxb + (size_t)(n - 768) * 300;
    for (int c = threadIdx.x; c < 80; c += 64) {
        u16x4 o = {0, 0, 0, 0};
        if (c < 75) {
            float4 x = *(const float4*)(src + c * 4);
            o[0] = f2bf(x.x); o[1] = f2bf(x.y); o[2] = f2bf(x.z); o[3] = f2bf(x.w);
        }
        *(u16x4*)(wxpad + (size_t)n * 320 + c * 4) = o;
    }
}

// ---------------------------------------------------------------------------
// build_bias: f32 bias2[1536] = bx + (gate r,z ? bh : 0).
// ROUND-9 FIX: c mod 768 via subtraction, NOT `c & 767` (768 != pow2).
// ---------------------------------------------------------------------------
__global__ __launch_bounds__(256) void build_bias(
    const float* __restrict__ bxf, const float* __restrict__ bhf,
    const float* __restrict__ bxb, const float* __restrict__ bhb,
    float* __restrict__ bias2)
{
    int c = blockIdx.x * 256 + threadIdx.x;
    if (c >= 1536) return;
    int cc = c < 768 ? c : c - 768;        // FIX (was c & 767)
    const float* bx = c < 768 ? bxf : bxb;
    const float* bh = c < 768 ? bhf : bhb;
    float v = bx[cc];
    if (cc < 512) v += bh[cc];             // fold bh into r,z gates only
    bias2[c] = v;
}

// ---------------------------------------------------------------------------
// stage_x: xstage[8192][320] bf16 = emb[inp[tok]] (f32), cols>=300 ZERO.
// ---------------------------------------------------------------------------
__global__ __launch_bounds__(64) void stage_x(
    const int* __restrict__ inp, const float* __restrict__ emb,
    u16* __restrict__ xstage)
{
    const int tok = blockIdx.x;
    const float* src = emb + (size_t)inp[tok] * 300;
    for (int c = threadIdx.x; c < 80; c += 64) {
        u16x4 o = {0, 0, 0, 0};
        if (c < 75) {
            float4 x = *(const float4*)(src + c * 4);
            o[0] = f2bf(x.x); o[1] = f2bf(x.y); o[2] = f2bf(x.z); o[3] = f2bf(x.w);
        }
        *(u16x4*)(xstage + (size_t)tok * 320 + c * 4) = o;
    }
}

// ---------------------------------------------------------------------------
// gemm128: C[M,Nout] = A[M,Kpad](bf16) * W[Npad,Kpad]^T + bias(f32, EPI=1).
// 128x128 tile, BK=32, 4 waves, global_load_lds 16B staging, linear LDS.
// M%128==0, Npad%128==0, Kpad%32==0. W rows >= Nout and cols >= real-K ZERO.
// ---------------------------------------------------------------------------
template<int EPI>
__global__ __launch_bounds__(256) void gemm128(
    const u16* __restrict__ A, const u16* __restrict__ W,
    const float* __restrict__ bias, u16* __restrict__ C,
    int Kpad, int Nout, int ldc)
{
    __shared__ __align__(16) u16 sA[128 * 32];
    __shared__ __align__(16) u16 sW[128 * 32];

    const int tid = threadIdx.x;
    const int n0 = blockIdx.x * 128;
    const int m0 = blockIdx.y * 128;

    const int l  = tid & 63;
    const int w  = tid >> 6;
    const int wm = (w >> 1) << 6;
    const int wn = (w & 1) << 6;
    const int fr = l & 15;
    const int fk = (l >> 4) << 3;

    const int srow = tid >> 2;
    const int scol = (tid & 3) << 3;

    f32x4 acc[4][4];
#pragma unroll
    for (int i = 0; i < 4; ++i)
#pragma unroll
        for (int j = 0; j < 4; ++j) acc[i][j] = (f32x4){0.f, 0.f, 0.f, 0.f};

    for (int k0 = 0; k0 < Kpad; k0 += 32) {
        __syncthreads();
#pragma unroll
        for (int i = 0; i < 2; ++i) {
            gload16(A + (size_t)(m0 + i * 64 + srow) * Kpad + k0 + scol,
                    sA + i * 2048 + tid * 8);
            gload16(W + (size_t)(n0 + i * 64 + srow) * Kpad + k0 + scol,
                    sW + i * 2048 + tid * 8);
        }
        __syncthreads();   // compiler drains vmcnt before s_barrier

        bf16x8 a[4], b[4];
#pragma unroll
        for (int i = 0; i < 4; ++i) {
            a[i] = *(const bf16x8*)(sA + (wm + i * 16 + fr) * 32 + fk);
            b[i] = *(const bf16x8*)(sW + (wn + i * 16 + fr) * 32 + fk);
        }
#pragma unroll
        for (int i = 0; i < 4; ++i)
#pragma unroll
            for (int j = 0; j < 4; ++j)
                acc[i][j] = __builtin_amdgcn_mfma_f32_16x16x32_bf16(a[i], b[j], acc[i][j], 0, 0, 0);
    }

    const int rb = (l >> 4) << 2;
    const int cc = l & 15;
#pragma unroll
    for (int j = 0; j < 4; ++j) {
        const int col = n0 + wn + j * 16 + cc;
        if (col < Nout) {
            const float bv = (EPI == 1) ? bias[col] : 0.f;
#pragma unroll
            for (int i = 0; i < 4; ++i) {
#pragma unroll
                for (int r = 0; r < 4; ++r) {
                    const int row = m0 + wm + i * 16 + rb + r;
                    C[(size_t)row * ldc + col] = f2bf(acc[i][j][r] + bv);
                }
            }
        }
    }
}

// ---------------------------------------------------------------------------
// gemm_bt (64^2 verified): used for ctx (N=300, K=512). bf16 bias.
// ---------------------------------------------------------------------------
__global__ __launch_bounds__(256) void gemm_bt(
    const u16* __restrict__ A, const u16* __restrict__ W,
    const u16* __restrict__ bias, u16* __restrict__ Cb,
    int M, int N, int K, int lda, int ldc)
{
    __shared__ __align__(16) u16 sA[64 * 40];
    __shared__ __align__(16) u16 sW[64 * 40];

    const int tid = threadIdx.x;
    const int m0 = blockIdx.y * 64;
    const int n0 = blockIdx.x * 64;

    const int l  = tid & 63;
    const int w  = tid >> 6;
    const int wm = (w >> 1) << 5;
    const int wn = (w & 1) << 5;
    const int fr = l & 15;
    const int fk = (l >> 4) << 3;

    const int sr = tid >> 2;
    const int cb = (tid & 3) << 3;

    const size_t abase = (size_t)(m0 + sr) * (size_t)lda;
    const int  wrow   = n0 + sr;
    const bool wvalid = wrow < N;
    const size_t wbase = (size_t)wrow * (size_t)K;

    f32x4 acc00 = {0,0,0,0}, acc01 = {0,0,0,0}, acc10 = {0,0,0,0}, acc11 = {0,0,0,0};

    for (int k0 = 0; k0 < K; k0 += 32) {
        __syncthreads();
        {
            const u16* p = A + abase + k0 + cb;
            *(u16x4*)(sA + sr * 40 + cb)     = *(const u16x4*)p;
            *(u16x4*)(sA + sr * 40 + cb + 4) = *(const u16x4*)(p + 4);
        }
        {
            u16x4 v0 = {0,0,0,0}, v1 = {0,0,0,0};
            if (wvalid) {
                const u16* p = W + wbase + k0 + cb;
                v0 = *(const u16x4*)p;
                v1 = *(const u16x4*)(p + 4);
            }
            *(u16x4*)(sW + sr * 40 + cb)     = v0;
            *(u16x4*)(sW + sr * 40 + cb + 4) = v1;
        }
        __syncthreads();

        bf16x8 a0 = *(const bf16x8*)(sA + (wm + fr)      * 40 + fk);
        bf16x8 a1 = *(const bf16x8*)(sA + (wm + 16 + fr) * 40 + fk);
        bf16x8 b0 = *(const bf16x8*)(sW + (wn + fr)      * 40 + fk);
        bf16x8 b1 = *(const bf16x8*)(sW + (wn + 16 + fr) * 40 + fk);

        acc00 = __builtin_amdgcn_mfma_f32_16x16x32_bf16(a0, b0, acc00, 0, 0, 0);
        acc01 = __builtin_amdgcn_mfma_f32_16x16x32_bf16(a0, b1, acc01, 0, 0, 0);
        acc10 = __builtin_amdgcn_mfma_f32_16x16x32_bf16(a1, b0, acc10, 0, 0, 0);
        acc11 = __builtin_amdgcn_mfma_f32_16x16x32_bf16(a1, b1, acc11, 0, 0, 0);
    }

    const int rb = (l >> 4) << 2;
    const int cc = l & 15;
#define EPILOG(ACC, I, J)                                                     \
    {                                                                         \
        int col = n0 + wn + (J)*16 + cc;                                      \
        if (col < N) {                                                        \
            float bv = bf2f(bias[col]);                                       \
            _Pragma("unroll")                                                 \
            for (int r = 0; r < 4; ++r) {                                     \
                int row = m0 + wm + (I)*16 + rb + r;                          \
                if (row < M)                                                  \
                    Cb[(size_t)row * ldc + col] = f2bf(ACC[r] + bv);          \
            }                                                                 \
        }                                                                     \
    }
    EPILOG(acc00, 0, 0); EPILOG(acc01, 0, 1); EPILOG(acc10, 1, 0); EPILOG(acc11, 1, 1);
#undef EPILOG
}

// ---------------------------------------------------------------------------
// GRU scan v3: MFMA + register-PINNED Wh + liveness diet.
// xg contains folded bx + bh_{r,z}; bhn kept in 4 f32 regs.
// ---------------------------------------------------------------------------
#define GB 8
__global__ __launch_bounds__(512, 2) void gru_scan_mfma(
    const u16* __restrict__ xg,           // [8192][1536]
    const u16* __restrict__ whf, const u16* __restrict__ whb,
    const float* __restrict__ bhf, const float* __restrict__ bhb,
    u16* __restrict__ outb)
{
    const int bg  = blockIdx.x;
    const int dir = blockIdx.y;
    const u16* wh = dir ? whb : whf;
    const float* bh = dir ? bhb : bhf;

    const int tid = threadIdx.x;
    const int w = tid >> 6;
    const int l = tid & 63;

    __shared__ __align__(16) u16 h_bf[16][264];   // rows 8..15 stay zero
    __shared__ __align__(16) float gh[GB][772];

    for (int i = tid; i < 16 * 264; i += 512) ((u16*)h_bf)[i] = 0;

    bf16x8 bfr[6][8];
#pragma unroll
    for (int c = 0; c < 6; ++c)
#pragma unroll
        for (int kt = 0; kt < 8; ++kt) {
            const int n = w * 96 + c * 16 + (l & 15);
            const int k = kt * 32 + (l >> 4) * 8;
            bfr[c][kt] = *(const bf16x8*)(wh + (size_t)n * 256 + k);
        }
#pragma unroll
    for (int c = 0; c < 6; ++c)
#pragma unroll
        for (int kt = 0; kt < 8; ++kt)
            asm volatile("" : "+v"(bfr[c][kt]));   // pin: no remat

    const int qrow = (l >> 4) << 2;
    const int arow = l & 15;
    const int aofs = (l >> 4) << 3;
    const int j0 = l * 4;
    const int bglob = bg * GB + w;
    const float4 bhn4 = *(const float4*)(bh + 512 + j0);
    f32x4 hreg = {0.f, 0.f, 0.f, 0.f};

    __syncthreads();

    for (int s = 0; s < 128; ++s) {
        const int t = dir ? (127 - s) : s;

        f32x4 acc[6];
#pragma unroll
        for (int c = 0; c < 6; ++c) acc[c] = (f32x4){0.f, 0.f, 0.f, 0.f};
#pragma unroll
        for (int kt = 0; kt < 8; ++kt) {
            bf16x8 a = *(const bf16x8*)(&h_bf[arow][kt * 32 + aofs]);
#pragma unroll
            for (int c = 0; c < 6; ++c)
                acc[c] = __builtin_amdgcn_mfma_f32_16x16x32_bf16(a, bfr[c][kt], acc[c], 0, 0, 0);
        }

        const size_t tb = (size_t)(bglob * 128 + t) * 1536 + dir * 768;
        u16x4 xr4 = *(const u16x4*)(xg + tb + j0);
        u16x4 xz4 = *(const u16x4*)(xg + tb + 256 + j0);
        u16x4 xn4 = *(const u16x4*)(xg + tb + 512 + j0);

        if (qrow < GB) {
#pragma unroll
            for (int c = 0; c < 6; ++c) {
                const int col = w * 96 + c * 16 + (l & 15);
#pragma unroll
                for (int r = 0; r < 4; ++r)
                    gh[qrow + r][col] = acc[c][r];
            }
        }
        __syncthreads();

        u16x4 ho;
#pragma unroll
        for (int e = 0; e < 4; ++e) {
            const int j = j0 + e;
            float r = sigm(bf2f(xr4[e]) + gh[w][j]);
            float z = sigm(bf2f(xz4[e]) + gh[w][256 + j]);
            float n = tanh_(bf2f(xn4[e]) + r * (gh[w][512 + j] + bhn4[e]));
            float h2 = (1.f - z) * n + z * hreg[e];
            hreg[e] = h2;
            ho[e] = f2bf(h2);
        }
        *(u16x4*)(&h_bf[w][j0]) = ho;
        *(u16x4*)(outb + (size_t)(bglob * 128 + t) * 512 + dir * 256 + j0) = ho;
        __syncthreads();
    }
}
#undef GB

// ---------------------------------------------------------------------------
// Concept attention. ctab f32. feat stride 640: ctx [0,300), concept
// [300,600), pad cols [600,640) ZEROED here (P GEMM reads them).
// ---------------------------------------------------------------------------
__global__ __launch_bounds__(256) void attn_kernel(
    const int* __restrict__ inp, const float* __restrict__ ctab,
    const int* __restrict__ mask16, u16* __restrict__ feat)
{
    const int tok = blockIdx.x;
    const int tid = threadIdx.x;
    const int v = inp[tok];

    __shared__ float ctx_s[300];
    __shared__ __align__(16) u16 conc_s[16 * 300];
    __shared__ float sc_s[16];
    __shared__ float at_s[16];

    for (int d = tid; d < 300; d += 256) ctx_s[d] = bf2f(feat[(size_t)tok * 640 + d]);
    {
        const float4* src = (const float4*)(ctab + (size_t)v * 4800);
        for (int i = tid; i < 1200; i += 256) {
            float4 x = src[i];
            u16x4 o; o[0] = f2bf(x.x); o[1] = f2bf(x.y); o[2] = f2bf(x.z); o[3] = f2bf(x.w);
            *(u16x4*)(conc_s + i * 4) = o;
        }
    }
    __syncthreads();

    const int g = tid >> 4, ln = tid & 15;
    float s = 0.f;
    for (int d = ln; d < 300; d += 16) s += bf2f(conc_s[g * 300 + d]) * ctx_s[d];
    s += __shfl_xor(s, 1); s += __shfl_xor(s, 2); s += __shfl_xor(s, 4); s += __shfl_xor(s, 8);
    if (ln == 0) sc_s[g] = ((mask16[v] >> g) & 1) ? s : -1e30f;
    __syncthreads();

    if (tid == 0) {
        float m = -1e30f;
#pragma unroll
        for (int i = 0; i < 16; ++i) m = fmaxf(m, sc_s[i]);
        float p[16]; float den = 0.f;
#pragma unroll
        for (int i = 0; i < 16; ++i) {
            float pe = (sc_s[i] <= -1e29f) ? 0.f : __expf(sc_s[i] - m);
            p[i] = pe; den += pe;
        }
        float inv = den > 0.f ? 1.f / den : 0.f;
#pragma unroll
        for (int i = 0; i < 16; ++i) at_s[i] = p[i] * inv;
    }
    __syncthreads();

    // writes cols 300..639: concept for d<300, ZERO for the 40 pad cols
    for (int d = tid; d < 340; d += 256) {
        float a = 0.f;
        if (d < 300) {
#pragma unroll
            for (int g2 = 0; g2 < 16; ++g2) a += at_s[g2] * bf2f(conc_s[g2 * 300 + d]);
        }
        feat[(size_t)tok * 640 + 300 + d] = f2bf(a);
    }
}

// ---------------------------------------------------------------------------
__global__ __launch_bounds__(128) void pool_fused(
    const u16* __restrict__ P, const u16* __restrict__ cbcat,
    float* __restrict__ pool)
{
    const int b = blockIdx.x, which = blockIdx.y, f = threadIdx.x;
    if (f >= 100) return;
    const int fs  = which == 0 ? 3 : (which == 1 ? 4 : 5);
    const int off = which == 0 ? 0 : (which == 1 ? 300 : 700);
    const int L   = 128 - fs + 1;
    const float bias = bf2f(cbcat[which * 100 + f]);
    float mm = -1e30f;
    for (int l2 = 0; l2 < L; ++l2) {
        float s = bias;
#pragma unroll 5
        for (int i = 0; i < fs; ++i)
            s += bf2f(P[(size_t)(b * 128 + l2 + i) * 1200 + off + i * 100 + f]);
        mm = fmaxf(mm, s);
    }
    pool[b * 300 + which * 100 + f] = fmaxf(mm, 0.f);
}

// ---------------------------------------------------------------------------
__global__ __launch_bounds__(128) void final_k(
    const float* __restrict__ pool,
    const u16* __restrict__ fc1W, const u16* __restrict__ fc1b,
    const u16* __restrict__ fc2W, const u16* __restrict__ fc2b,
    float* __restrict__ out)
{
    const int b = blockIdx.x, tid = threadIdx.x;
    __shared__ float ps[300], h1[100], lg[5];
    for (int d = tid; d < 300; d += 128) ps[d] = pool[b * 300 + d];
    __syncthreads();
    if (tid < 100) {
        float a = bf2f(fc1b[tid]);
        for (int k = 0; k < 300; ++k) a += bf2f(fc1W[tid * 300 + k]) * ps[k];
        h1[tid] = a;
    }
    __syncthreads();
    if (tid < 5) {
        float a = bf2f(fc2b[tid]);
        for (int k = 0; k < 100; ++k) a += bf2f(fc2W[tid * 100 + k]) * h1[k];
        lg[tid] = a;
    }
    __syncthreads();
    if (tid == 0) {
        float m = fmaxf(fmaxf(fmaxf(lg[0], lg[1]), fmaxf(lg[2], lg[3])), lg[4]);
        float e0 = __expf(lg[0] - m), e1 = __expf(lg[1] - m), e2 = __expf(lg[2] - m),
              e3 = __expf(lg[3] - m), e4 = __expf(lg[4] - m);
        float inv = 1.f / (e0 + e1 + e2 + e3 + e4);
        out[b * 5 + 0] = e0 * inv;
        out[b * 5 + 1] = e1 * inv;
        out[b * 5 + 2] = e2 * inv;
        out[b * 5 + 3] = e3 * inv;
        out[b * 5 + 4] = e4 * inv;
    }
}

// ---------------------------------------------------------------------------
extern "C" void kernel_launch(void* const* d_in, const int* in_sizes, int n_in,
                              void* d_out, int out_size, void* d_ws, size_t ws_size,
                              hipStream_t stream)
{
    (void)in_sizes; (void)n_in; (void)out_size; (void)ws_size;

    const int*  inp     = (const int*)d_in[0];
    const void* embR    = d_in[1];
    const void* WxfR    = d_in[2];
    const void* WhfR    = d_in[3];
    const void* bxfR    = d_in[4];
    const void* bhfR    = d_in[5];
    const void* WxbR    = d_in[6];
    const void* WhbR    = d_in[7];
    const void* bxbR    = d_in[8];
    const void* bhbR    = d_in[9];
    const void* fc1cWR  = d_in[10];
    const void* fc1cbR  = d_in[11];
    const void* ctabR   = d_in[12];
    const void* cmaskR  = d_in[13];
    const void* cw0R    = d_in[14];
    const void* cb0R    = d_in[15];
    const void* cw1R    = d_in[16];
    const void* cb1R    = d_in[17];
    const void* cw2R    = d_in[18];
    const void* cb2R    = d_in[19];
    const void* fc1WR   = d_in[20];
    const void* fc1bR   = d_in[21];
    const void* fc2WR   = d_in[22];
    const void* fc2bR   = d_in[23];

    char* ws = (char*)d_ws;
    size_t off = 0;
    auto alloc = [&](size_t bytes) -> char* {
        char* r = ws + off;
        off = (off + bytes + 255) & ~(size_t)255;
        return r;
    };

    u16*   xgc    = (u16*)alloc(8192ull * 1536 * 2);
    u16*   outb   = (u16*)alloc(8192ull * 512 * 2);
    u16*   feat   = (u16*)alloc(8192ull * 640 * 2);
    u16*   P      = (u16*)alloc(8192ull * 1200 * 2);
    u16*   xstage = (u16*)alloc(8192ull * 320 * 2);
    float* pool   = (float*)alloc(64ull * 300 * 4);
    int*   flags  = (int*)alloc(256);
    int*   mask16 = (int*)alloc(30000ull * 4);
    u16*   wxpad  = (u16*)alloc(1536ull * 320 * 2);
    float* bias2  = (float*)alloc(1536ull * 4);
    u16*   whfc   = (u16*)alloc(196608ull * 2);
    u16*   whbc   = (u16*)alloc(196608ull * 2);
    u16*   fc1cWc = (u16*)alloc(153600ull * 2);
    u16*   fc1cbc = (u16*)alloc(300ull * 2);
    u16*   wcat   = (u16*)alloc(1280ull * 640 * 2);
    u16*   cbcat  = (u16*)alloc(300ull * 2);
    u16*   fc1Wc  = (u16*)alloc(30000ull * 2);
    u16*   fc1bc  = (u16*)alloc(100ull * 2);
    u16*   fc2Wc  = (u16*)alloc(500ull * 2);
    u16*   fc2bc  = (u16*)alloc(8ull * 2);

    // 0) mask dtype detection
    detect_k<<<1, 256, 0, stream>>>((const u32*)cmaskR, flags);

    // 1) f32 -> bf16 weight conversions
    {
        CvtArgs a{};
        a.d[0]  = { WhfR,   whfc,        196608 };
        a.d[1]  = { WhbR,   whbc,        196608 };
        a.d[2]  = { fc1cWR, fc1cWc,      153600 };
        a.d[3]  = { fc1cbR, fc1cbc,      300 };
        a.d[4]  = { cb0R,   cbcat,       100 };
        a.d[5]  = { cb1R,   cbcat + 100, 100 };
        a.d[6]  = { cb2R,   cbcat + 200, 100 };
        a.d[7]  = { fc1WR,  fc1Wc,       30000 };
        a.d[8]  = { fc1bR,  fc1bc,       100 };
        a.d[9]  = { fc2WR,  fc2Wc,       500 };
        a.d[10] = { fc2bR,  fc2bc,       5 };
        convert_f32<<<dim3(192, 11), 256, 0, stream>>>(a);
    }

    // 2) prep
    build_mask<<<118, 256, 0, stream>>>(cmaskR, mask16, flags);
    repack_conv<<<1280, 256, 0, stream>>>(
        (const float*)cw0R, (const float*)cw1R, (const float*)cw2R, wcat);
    pack_wx<<<1536, 64, 0, stream>>>((const float*)WxfR, (const float*)WxbR, wxpad);
    build_bias<<<6, 256, 0, stream>>>((const float*)bxfR, (const float*)bhfR,
                                      (const float*)bxbR, (const float*)bhbR, bias2);
    stage_x<<<8192, 64, 0, stream>>>(inp, (const float*)embR, xstage);

    // 3) xg = x @ [Wx_f;Wx_b]^T + (bx + bh_{r,z})   [8192 x 1536], K=320
    gemm128<1><<<dim3(12, 64), 256, 0, stream>>>(
        xstage, wxpad, bias2, xgc, 320, 1536, 1536);

    // 4) bidirectional GRU scan -> outb [8192 x 512]
    gru_scan_mfma<<<dim3(8, 2), 512, 0, stream>>>(
        xgc, whfc, whbc, (const float*)bhfR, (const float*)bhbR, outb);

    // 5) ctx = outb @ fc1c_W^T + b -> feat[:, 0:300]  (ldc 640)
    gemm_bt<<<dim3(5, 128), 256, 0, stream>>>(
        outb, fc1cWc, fc1cbc, feat, 8192, 300, 512, 512, 640);

    // 6) concept attention -> feat[:, 300:600] (+ zero pad cols)
    attn_kernel<<<dim3(8192), 256, 0, stream>>>(inp, (const float*)ctabR, mask16, feat);

    // 7) P = feat @ Wcat^T   [8192 x 1200], Kpad=640
    gemm128<0><<<dim3(10, 64), 256, 0, stream>>>(
        feat, wcat, nullptr, P, 640, 1200, 1200);

    // 8) shift-add + bias + relu + maxpool
    pool_fused<<<dim3(64, 3), 128, 0, stream>>>(P, cbcat, pool);

    // 9) fc1 -> fc2 -> softmax -> d_out (f32)
    final_k<<<dim3(64), 128, 0, stream>>>(pool, fc1Wc, fc1bc, fc2Wc, fc2bc, (float*)d_out);
}